// Round 1
// baseline (1016.230 us; speedup 1.0000x reference)
//
#include <hip/hip_runtime.h>

typedef _Float16 f16x8 __attribute__((ext_vector_type(8)));
typedef float f32x4 __attribute__((ext_vector_type(4)));
#define HALF _Float16

// ---- weight conversion: fp32 (27,CI,CO) row-major -> fp16 transposed (CO_PAD, KP), zero padded
__global__ void convert_w_kernel(const float* __restrict__ W, HALF* __restrict__ Wt,
                                 int CI, int CO, int CO_PAD, int KP)
{
    int i = blockIdx.x * 256 + threadIdx.x;
    if (i >= CO_PAD * KP) return;
    int jp = i / KP;
    int kp = i - jp * KP;
    float v = 0.f;
    if (jp < CO && kp < 27 * CI) v = W[(size_t)kp * CO + jp];  // W flat: (27*CI, CO)
    Wt[i] = (HALF)v;
}

// ---- conv: y[n, CO_PAD] = gatherA(n, K) @ Wt(K, CO_PAD); also per-channel sum/sumsq atomics
template<int CI, int CO_PAD, bool INF32>
__global__ __launch_bounds__(256) void conv_kernel(
    const void* __restrict__ inbuf, const int* __restrict__ nbr,
    const HALF* __restrict__ Wt, HALF* __restrict__ yout,
    float* __restrict__ sums, int n)
{
    constexpr int KP = ((27 * CI + 31) / 32) * 32;  // K padded to 32
    constexpr int NJB = CO_PAD / 16;
    constexpr int AS = 40;                          // LDS row stride (halfs), pad vs 32

    __shared__ __align__(16) HALF As[64 * AS];
    __shared__ float red[2][4][CO_PAD];

    const int tid  = threadIdx.x;
    const int wave = tid >> 6;
    const int lane = tid & 63;
    const int l15  = lane & 15;
    const int lq   = lane >> 4;
    const int tileBase = blockIdx.x * 64;

    const int sr = tid >> 2;   // staging row 0..63
    const int sj = tid & 3;    // 8-half slot within 32-k chunk
    const int srow = tileBase + sr;

    f32x4 acc[NJB];
#pragma unroll
    for (int jb = 0; jb < NJB; ++jb)
#pragma unroll
        for (int r = 0; r < 4; ++r) acc[jb][r] = 0.f;

    for (int k0 = 0; k0 < KP; k0 += 32) {
        // ---- stage gathered A chunk (64 rows x 32 k) into LDS
        const int kbase = k0 + sj * 8;
        const int t = kbase / CI;
        const int c = kbase - t * CI;
        int idx = -1;
        if (srow < n && t < 27) idx = nbr[srow * 27 + t];
        uint4 v = {0u, 0u, 0u, 0u};
        if (idx >= 0) {
            if constexpr (INF32) {
                const float* src = (const float*)inbuf + (size_t)idx * CI + c;
                const float4 f0 = ((const float4*)src)[0];
                const float4 f1 = ((const float4*)src)[1];
                union { HALF h[8]; uint4 u4; } u;
                u.h[0] = (HALF)f0.x; u.h[1] = (HALF)f0.y; u.h[2] = (HALF)f0.z; u.h[3] = (HALF)f0.w;
                u.h[4] = (HALF)f1.x; u.h[5] = (HALF)f1.y; u.h[6] = (HALF)f1.z; u.h[7] = (HALF)f1.w;
                v = u.u4;
            } else {
                v = *(const uint4*)((const HALF*)inbuf + (size_t)idx * CI + c);
            }
        }
        *(uint4*)&As[sr * AS + sj * 8] = v;
        __syncthreads();

        // ---- fragments + MFMA. A[m=lane&15][k=(lane>>4)*8+j]; B[k][n=lane&15] from Wt[n][k]
        const f16x8 a = *(const f16x8*)&As[(wave * 16 + l15) * AS + lq * 8];
        const int kf = k0 + lq * 8;
#pragma unroll
        for (int jb = 0; jb < NJB; ++jb) {
            const f16x8 b = *(const f16x8*)&Wt[(size_t)(jb * 16 + l15) * KP + kf];
            acc[jb] = __builtin_amdgcn_mfma_f32_16x16x32_f16(a, b, acc[jb], 0, 0, 0);
        }
        __syncthreads();
    }

    // ---- epilogue: store pre-norm y (fp16) + per-channel sum/sumsq
    // C/D layout: col = lane&15, row = (lane>>4)*4 + reg
#pragma unroll
    for (int jb = 0; jb < NJB; ++jb) {
        const int col = jb * 16 + l15;
        const int rbase = tileBase + wave * 16 + lq * 4;
        float s = 0.f, sq = 0.f;
#pragma unroll
        for (int r = 0; r < 4; ++r) {
            const float vv = acc[jb][r];
            if (rbase + r < n) {
                yout[(size_t)(rbase + r) * CO_PAD + col] = (HALF)vv;
                s += vv;
                sq += vv * vv;
            }
        }
        s  += __shfl_xor(s, 16);  s  += __shfl_xor(s, 32);
        sq += __shfl_xor(sq, 16); sq += __shfl_xor(sq, 32);
        if (lane < 16) { red[0][wave][col] = s; red[1][wave][col] = sq; }
    }
    __syncthreads();
    if (tid < CO_PAD) {
        const float s  = red[0][0][tid] + red[0][1][tid] + red[0][2][tid] + red[0][3][tid];
        const float sq = red[1][0][tid] + red[1][1][tid] + red[1][2][tid] + red[1][3][tid];
        atomicAdd(&sums[tid], s);
        atomicAdd(&sums[CO_PAD + tid], sq);
    }
}

// ---- in-place batchnorm + relu (CO == CO_PAD for all users of this kernel)
template<int CO_PAD, bool RELU>
__global__ void bn_apply_kernel(HALF* __restrict__ y, const float* __restrict__ sums,
                                const float* __restrict__ g, const float* __restrict__ b,
                                int n, float invn)
{
    int i = blockIdx.x * 256 + threadIdx.x;
    if (i >= n * CO_PAD) return;
    int c = i & (CO_PAD - 1);
    float mu  = sums[c] * invn;
    float var = sums[CO_PAD + c] * invn - mu * mu;
    float sc  = rsqrtf(var + 1e-3f) * g[c];
    float v = ((float)y[i] - mu) * sc + b[c];
    if (RELU) v = fmaxf(v, 0.f);
    y[i] = (HALF)v;
}

// ---- final: normalize (no relu), co=3 out of CO_PAD=16, fp32 output
__global__ void bn_out_kernel(const HALF* __restrict__ y, const float* __restrict__ sums,
                              const float* __restrict__ g, const float* __restrict__ b,
                              int n, float invn, float* __restrict__ out)
{
    int i = blockIdx.x * 256 + threadIdx.x;
    if (i >= n * 3) return;
    int row = i / 3;
    int c = i - row * 3;
    float mu  = sums[c] * invn;
    float var = sums[16 + c] * invn - mu * mu;
    float sc  = rsqrtf(var + 1e-3f) * g[c];
    out[i] = ((float)y[row * 16 + c] - mu) * sc + b[c];
}

extern "C" void kernel_launch(void* const* d_in, const int* in_sizes, int n_in,
                              void* d_out, int out_size, void* d_ws, size_t ws_size,
                              hipStream_t stream)
{
    const int* nbr4  = (const int*)d_in[0];
    const int* inv43 = (const int*)d_in[1];
    const int* nbr3  = (const int*)d_in[2];
    const int* inv32 = (const int*)d_in[3];
    const int* nbr2  = (const int*)d_in[4];
    const int* inv21 = (const int*)d_in[5];
    const int* nbr1  = (const int*)d_in[6];
    const float* x   = (const float*)d_in[7];

    const int n4 = in_sizes[0] / 27;
    const int n3 = in_sizes[1] / 27;
    const int n2 = in_sizes[3] / 27;
    const int n1 = in_sizes[5] / 27;

    // specs: m4,i4,m3,i3,m2,i2,m1,c5
    const int CIs[8]  = {64, 64, 64, 64, 32, 32, 16, 16};
    const int COs[8]  = {64, 64, 64, 32, 32, 16, 16, 3};
    const int COPs[8] = {64, 64, 64, 32, 32, 16, 16, 16};
    int KPs[8], wtoff[8];
    int wtot = 0;
    for (int s = 0; s < 8; ++s) {
        KPs[s] = ((27 * CIs[s] + 31) / 32) * 32;
        wtoff[s] = wtot;
        wtot += COPs[s] * KPs[s];
    }

    char* ws = (char*)d_ws;
    HALF* wt = (HALF*)ws;
    size_t off = ((size_t)wtot * sizeof(HALF) + 255) & ~(size_t)255;
    float* sums = (float*)(ws + off);
    off += 8 * 128 * sizeof(float);
    off = (off + 255) & ~(size_t)255;
    size_t bufElems = 0;
    {
        size_t cand[4] = {(size_t)n4 * 64, (size_t)n3 * 64, (size_t)n2 * 32, (size_t)n1 * 16};
        for (int i = 0; i < 4; ++i) if (cand[i] > bufElems) bufElems = cand[i];
    }
    HALF* Y0 = (HALF*)(ws + off);
    off += (bufElems * sizeof(HALF) + 255) & ~(size_t)255;
    HALF* Y1 = (HALF*)(ws + off);

    hipMemsetAsync(sums, 0, 8 * 128 * sizeof(float), stream);

    for (int s = 0; s < 8; ++s) {
        const float* W = (const float*)d_in[8 + 3 * s];
        int total = COPs[s] * KPs[s];
        convert_w_kernel<<<(total + 255) / 256, 256, 0, stream>>>(W, wt + wtoff[s], CIs[s], COs[s], COPs[s], KPs[s]);
    }

#define GB(s) (const float*)d_in[9 + 3 * (s)], (const float*)d_in[10 + 3 * (s)]

    // m4: x(n4,64) -> Y0
    conv_kernel<64, 64, true><<<(n4 + 63) / 64, 256, 0, stream>>>(x, nbr4, wt + wtoff[0], Y0, sums + 0 * 128, n4);
    bn_apply_kernel<64, true><<<(n4 * 64 + 255) / 256, 256, 0, stream>>>(Y0, sums + 0 * 128, GB(0), n4, 1.f / n4);
    // i4: Y0(n4) -> Y1(n3)
    conv_kernel<64, 64, false><<<(n3 + 63) / 64, 256, 0, stream>>>(Y0, inv43, wt + wtoff[1], Y1, sums + 1 * 128, n3);
    bn_apply_kernel<64, true><<<(n3 * 64 + 255) / 256, 256, 0, stream>>>(Y1, sums + 1 * 128, GB(1), n3, 1.f / n3);
    // m3: Y1 -> Y0
    conv_kernel<64, 64, false><<<(n3 + 63) / 64, 256, 0, stream>>>(Y1, nbr3, wt + wtoff[2], Y0, sums + 2 * 128, n3);
    bn_apply_kernel<64, true><<<(n3 * 64 + 255) / 256, 256, 0, stream>>>(Y0, sums + 2 * 128, GB(2), n3, 1.f / n3);
    // i3: Y0(n3) -> Y1(n2), co 32
    conv_kernel<64, 32, false><<<(n2 + 63) / 64, 256, 0, stream>>>(Y0, inv32, wt + wtoff[3], Y1, sums + 3 * 128, n2);
    bn_apply_kernel<32, true><<<(n2 * 32 + 255) / 256, 256, 0, stream>>>(Y1, sums + 3 * 128, GB(3), n2, 1.f / n2);
    // m2: Y1 -> Y0
    conv_kernel<32, 32, false><<<(n2 + 63) / 64, 256, 0, stream>>>(Y1, nbr2, wt + wtoff[4], Y0, sums + 4 * 128, n2);
    bn_apply_kernel<32, true><<<(n2 * 32 + 255) / 256, 256, 0, stream>>>(Y0, sums + 4 * 128, GB(4), n2, 1.f / n2);
    // i2: Y0(n2) -> Y1(n1), co 16
    conv_kernel<32, 16, false><<<(n1 + 63) / 64, 256, 0, stream>>>(Y0, inv21, wt + wtoff[5], Y1, sums + 5 * 128, n1);
    bn_apply_kernel<16, true><<<(n1 * 16 + 255) / 256, 256, 0, stream>>>(Y1, sums + 5 * 128, GB(5), n1, 1.f / n1);
    // m1: Y1 -> Y0
    conv_kernel<16, 16, false><<<(n1 + 63) / 64, 256, 0, stream>>>(Y1, nbr1, wt + wtoff[6], Y0, sums + 6 * 128, n1);
    bn_apply_kernel<16, true><<<(n1 * 16 + 255) / 256, 256, 0, stream>>>(Y0, sums + 6 * 128, GB(6), n1, 1.f / n1);
    // c5: Y0 -> Y1 (pre-norm), then fp32 out
    conv_kernel<16, 16, false><<<(n1 + 63) / 64, 256, 0, stream>>>(Y0, nbr1, wt + wtoff[7], Y1, sums + 7 * 128, n1);
    bn_out_kernel<<<(n1 * 3 + 255) / 256, 256, 0, stream>>>(Y1, sums + 7 * 128, GB(7), n1, 1.f / n1, (float*)d_out);

#undef GB
}

// Round 2
// 767.018 us; speedup vs baseline: 1.3249x; 1.3249x over previous
//
#include <hip/hip_runtime.h>

typedef _Float16 HALF;
typedef _Float16 f16x8 __attribute__((ext_vector_type(8)));
typedef float f32x4 __attribute__((ext_vector_type(4)));

// ---- fused weight conversion: fp32 (27*CI, CO) -> fp16 tiled [KP/32][CO_PAD][32], zero padded
struct WArgs { const float* W[8]; HALF* dst[8]; };

__global__ void convert_all_w_kernel(WArgs a)
{
    const int CIs[8]  = {64, 64, 64, 64, 32, 32, 16, 16};
    const int COs[8]  = {64, 64, 64, 32, 32, 16, 16, 3};
    const int COPs[8] = {64, 64, 64, 32, 32, 16, 16, 16};
    const int L = blockIdx.y;
    const int CI = CIs[L], CO = COs[L], COP = COPs[L];
    const int K = 27 * CI, KP = (K + 31) & ~31;
    const int total = COP * KP;
    for (int i = blockIdx.x * 256 + threadIdx.x; i < total; i += gridDim.x * 256) {
        int jp = i / KP;          // out channel (padded)
        int kp = i - jp * KP;     // k (padded)
        float v = (jp < CO && kp < K) ? a.W[L][(size_t)kp * CO + jp] : 0.f;
        a.dst[L][((size_t)(kp >> 5) * COP + jp) * 32 + (kp & 31)] = (HALF)v;
    }
}

__global__ void convert_x_kernel(const float* __restrict__ x, HALF* __restrict__ xh, int total)
{
    int i = blockIdx.x * 256 + threadIdx.x;
    if (i < total) xh[i] = (HALF)x[i];
}

// ---- conv: barrier-free main loop, direct global->register gather of MFMA fragments
template<int CI, int CO_PAD, int NMT>
__global__ __launch_bounds__(256) void conv_kernel(
    const HALF* __restrict__ h, const int* __restrict__ nbr,
    const HALF* __restrict__ Wt, HALF* __restrict__ yout,
    float* __restrict__ sums, int n)
{
    constexpr int K   = 27 * CI;
    constexpr int KP  = (K + 31) & ~31;
    constexpr int NCH = KP / 32;
    constexpr int NJB = CO_PAD / 16;
    constexpr int NW  = 4;                 // waves per block

    __shared__ float red[2][NW][CO_PAD];

    const int wv   = threadIdx.x >> 6;
    const int lane = threadIdx.x & 63;
    const int l15  = lane & 15;
    const int lq   = lane >> 4;
    const int waveRow = (blockIdx.x * NW + wv) * (16 * NMT);

    f32x4 acc[NMT][NJB];
#pragma unroll
    for (int mt = 0; mt < NMT; ++mt)
#pragma unroll
        for (int jb = 0; jb < NJB; ++jb)
#pragma unroll
            for (int r = 0; r < 4; ++r) acc[mt][jb][r] = 0.f;

    // per-m-tile nbr base for this lane's row (row = waveRow + mt*16 + l15)
    int nbase[NMT];
#pragma unroll
    for (int mt = 0; mt < NMT; ++mt) {
        const int row = waveRow + mt * 16 + l15;
        nbase[mt] = (row < n) ? row * 27 : -1;
    }

    for (int kc = 0; kc < NCH; ++kc) {
        const int kf = kc * 32 + lq * 8;   // this lane's k within [0,KP)
        const int t  = kf / CI;            // tap (constant over the 8 contiguous k)
        const int c  = kf - t * CI;        // channel offset within tap

        // B fragments: coalesced from tiled Wt
        const HALF* wb = Wt + (size_t)kc * CO_PAD * 32 + lq * 8;
        f16x8 b[NJB];
#pragma unroll
        for (int jb = 0; jb < NJB; ++jb)
            b[jb] = *(const f16x8*)(wb + (size_t)(jb * 16 + l15) * 32);

#pragma unroll
        for (int mt = 0; mt < NMT; ++mt) {
            int idx = -1;
            if (nbase[mt] >= 0 && t < 27) idx = nbr[nbase[mt] + t];
            f16x8 a;
#pragma unroll
            for (int j = 0; j < 8; ++j) a[j] = (HALF)0.f;
            if (idx >= 0) a = *(const f16x8*)(h + (size_t)idx * CI + c);
#pragma unroll
            for (int jb = 0; jb < NJB; ++jb)
                acc[mt][jb] = __builtin_amdgcn_mfma_f32_16x16x32_f16(a, b[jb], acc[mt][jb], 0, 0, 0);
        }
    }

    // ---- epilogue: store pre-norm y (fp16) + per-channel sum/sumsq
    // C/D layout: col = lane&15, row = (lane>>4)*4 + reg
#pragma unroll
    for (int jb = 0; jb < NJB; ++jb) {
        const int col = jb * 16 + l15;
        float s = 0.f, sq = 0.f;
#pragma unroll
        for (int mt = 0; mt < NMT; ++mt) {
            const int rb = waveRow + mt * 16 + lq * 4;
#pragma unroll
            for (int r = 0; r < 4; ++r) {
                if (rb + r < n) {
                    const float v = acc[mt][jb][r];
                    yout[(size_t)(rb + r) * CO_PAD + col] = (HALF)v;
                    s += v;
                    sq += v * v;
                }
            }
        }
        s  += __shfl_xor(s, 16);  s  += __shfl_xor(s, 32);
        sq += __shfl_xor(sq, 16); sq += __shfl_xor(sq, 32);
        if (lane < 16) { red[0][wv][col] = s; red[1][wv][col] = sq; }
    }
    __syncthreads();
    if (threadIdx.x < CO_PAD) {
        float s = 0.f, sq = 0.f;
#pragma unroll
        for (int w = 0; w < NW; ++w) { s += red[0][w][threadIdx.x]; sq += red[1][w][threadIdx.x]; }
        atomicAdd(&sums[threadIdx.x], s);
        atomicAdd(&sums[CO_PAD + threadIdx.x], sq);
    }
}

// ---- in-place batchnorm + relu, 8 halfs per thread
template<int CO_PAD, bool RELU>
__global__ void bn_apply_kernel(HALF* __restrict__ y, const float* __restrict__ sums,
                                const float* __restrict__ g, const float* __restrict__ b,
                                int n, float invn)
{
    const int i = blockIdx.x * 256 + threadIdx.x;
    const int total = n * CO_PAD / 8;
    if (i >= total) return;
    f16x8 v = *(f16x8*)(y + (size_t)i * 8);
    const int c0 = (i * 8) & (CO_PAD - 1);
#pragma unroll
    for (int j = 0; j < 8; ++j) {
        const int c = c0 + j;
        const float mu  = sums[c] * invn;
        const float var = sums[CO_PAD + c] * invn - mu * mu;
        const float sc  = rsqrtf(var + 1e-3f) * g[c];
        float f = ((float)v[j] - mu) * sc + b[c];
        if (RELU) f = fmaxf(f, 0.f);
        v[j] = (HALF)f;
    }
    *(f16x8*)(y + (size_t)i * 8) = v;
}

// ---- final: normalize (no relu), co=3 out of CO_PAD=16, fp32 output
__global__ void bn_out_kernel(const HALF* __restrict__ y, const float* __restrict__ sums,
                              const float* __restrict__ g, const float* __restrict__ b,
                              int n, float invn, float* __restrict__ out)
{
    int i = blockIdx.x * 256 + threadIdx.x;
    if (i >= n * 3) return;
    int row = i / 3;
    int c = i - row * 3;
    float mu  = sums[c] * invn;
    float var = sums[16 + c] * invn - mu * mu;
    float sc  = rsqrtf(var + 1e-3f) * g[c];
    out[i] = ((float)y[(size_t)row * 16 + c] - mu) * sc + b[c];
}

extern "C" void kernel_launch(void* const* d_in, const int* in_sizes, int n_in,
                              void* d_out, int out_size, void* d_ws, size_t ws_size,
                              hipStream_t stream)
{
    const int* nbr4  = (const int*)d_in[0];
    const int* inv43 = (const int*)d_in[1];
    const int* nbr3  = (const int*)d_in[2];
    const int* inv32 = (const int*)d_in[3];
    const int* nbr2  = (const int*)d_in[4];
    const int* inv21 = (const int*)d_in[5];
    const int* nbr1  = (const int*)d_in[6];
    const float* x   = (const float*)d_in[7];

    const int n4 = in_sizes[0] / 27;
    const int n3 = in_sizes[1] / 27;
    const int n2 = in_sizes[3] / 27;
    const int n1 = in_sizes[5] / 27;

    // specs: m4,i4,m3,i3,m2,i2,m1,c5
    const int CIs[8]  = {64, 64, 64, 64, 32, 32, 16, 16};
    const int COPs[8] = {64, 64, 64, 32, 32, 16, 16, 16};
    int KPs[8], wtoff[8];
    int wtot = 0;
    for (int s = 0; s < 8; ++s) {
        KPs[s] = ((27 * CIs[s] + 31) / 32) * 32;
        wtoff[s] = wtot;
        wtot += COPs[s] * KPs[s];
    }

    char* ws = (char*)d_ws;
    HALF* wt = (HALF*)ws;
    size_t off = ((size_t)wtot * sizeof(HALF) + 255) & ~(size_t)255;
    float* sums = (float*)(ws + off);
    off += 8 * 128 * sizeof(float);
    off = (off + 255) & ~(size_t)255;
    HALF* xh = (HALF*)(ws + off);
    off += ((size_t)n4 * 64 * sizeof(HALF) + 255) & ~(size_t)255;
    size_t bufElems = 0;
    {
        size_t cand[4] = {(size_t)n4 * 64, (size_t)n3 * 64, (size_t)n2 * 32, (size_t)n1 * 16};
        for (int i = 0; i < 4; ++i) if (cand[i] > bufElems) bufElems = cand[i];
    }
    HALF* Y0 = (HALF*)(ws + off);
    off += (bufElems * sizeof(HALF) + 255) & ~(size_t)255;
    HALF* Y1 = (HALF*)(ws + off);

    hipMemsetAsync(sums, 0, 8 * 128 * sizeof(float), stream);

    // fused weight conversion (one node)
    WArgs wa;
    for (int s = 0; s < 8; ++s) { wa.W[s] = (const float*)d_in[8 + 3 * s]; wa.dst[s] = wt + wtoff[s]; }
    {
        int maxTotal = 64 * KPs[0];  // 112640
        dim3 grid((maxTotal + 255) / 256, 8);
        convert_all_w_kernel<<<grid, 256, 0, stream>>>(wa);
    }
    convert_x_kernel<<<(n4 * 64 + 255) / 256, 256, 0, stream>>>(x, xh, n4 * 64);

#define GB(s) (const float*)d_in[9 + 3 * (s)], (const float*)d_in[10 + 3 * (s)]
#define CONV(CI, COP, NMT, in, nb, s, out, nn) \
    conv_kernel<CI, COP, NMT><<<((nn) + 4 * 16 * NMT - 1) / (4 * 16 * NMT), 256, 0, stream>>>( \
        in, nb, wt + wtoff[s], out, sums + (s) * 128, nn)

    // m4: xh(n4,64) -> Y0
    CONV(64, 64, 4, xh, nbr4, 0, Y0, n4);
    bn_apply_kernel<64, true><<<(n4 * 8 + 255) / 256, 256, 0, stream>>>(Y0, sums + 0 * 128, GB(0), n4, 1.f / n4);
    // i4: Y0(n4) -> Y1(n3)
    CONV(64, 64, 4, Y0, inv43, 1, Y1, n3);
    bn_apply_kernel<64, true><<<(n3 * 8 + 255) / 256, 256, 0, stream>>>(Y1, sums + 1 * 128, GB(1), n3, 1.f / n3);
    // m3: Y1 -> Y0
    CONV(64, 64, 4, Y1, nbr3, 2, Y0, n3);
    bn_apply_kernel<64, true><<<(n3 * 8 + 255) / 256, 256, 0, stream>>>(Y0, sums + 2 * 128, GB(2), n3, 1.f / n3);
    // i3: Y0(n3) -> Y1(n2), co 32
    CONV(64, 32, 8, Y0, inv32, 3, Y1, n2);
    bn_apply_kernel<32, true><<<(n2 * 4 + 255) / 256, 256, 0, stream>>>(Y1, sums + 3 * 128, GB(3), n2, 1.f / n2);
    // m2: Y1 -> Y0
    CONV(32, 32, 8, Y1, nbr2, 4, Y0, n2);
    bn_apply_kernel<32, true><<<(n2 * 4 + 255) / 256, 256, 0, stream>>>(Y0, sums + 4 * 128, GB(4), n2, 1.f / n2);
    // i2: Y0(n2) -> Y1(n1), co 16
    CONV(32, 16, 8, Y0, inv21, 5, Y1, n1);
    bn_apply_kernel<16, true><<<(n1 * 2 + 255) / 256, 256, 0, stream>>>(Y1, sums + 5 * 128, GB(5), n1, 1.f / n1);
    // m1: Y1 -> Y0
    CONV(16, 16, 8, Y1, nbr1, 6, Y0, n1);
    bn_apply_kernel<16, true><<<(n1 * 2 + 255) / 256, 256, 0, stream>>>(Y0, sums + 6 * 128, GB(6), n1, 1.f / n1);
    // c5: Y0 -> Y1 (pre-norm), then fp32 out
    CONV(16, 16, 8, Y0, nbr1, 7, Y1, n1);
    bn_out_kernel<<<(n1 * 3 + 255) / 256, 256, 0, stream>>>(Y1, sums + 7 * 128, GB(7), n1, 1.f / n1, (float*)d_out);

#undef CONV
#undef GB
}

// Round 3
// 594.282 us; speedup vs baseline: 1.7100x; 1.2907x over previous
//
#include <hip/hip_runtime.h>

typedef _Float16 HALF;
typedef _Float16 f16x8 __attribute__((ext_vector_type(8)));
typedef float f32x4 __attribute__((ext_vector_type(4)));

// ---- fused weight conversion: fp32 (27*CI, CO) -> fp16 tiled [KP/32][CO_PAD][32], zero padded
struct WArgs { const float* W[8]; HALF* dst[8]; };

__global__ void convert_all_w_kernel(WArgs a)
{
    const int CIs[8]  = {64, 64, 64, 64, 32, 32, 16, 16};
    const int COs[8]  = {64, 64, 64, 32, 32, 16, 16, 3};
    const int COPs[8] = {64, 64, 64, 32, 32, 16, 16, 16};
    const int L = blockIdx.y;
    const int CI = CIs[L], CO = COs[L], COP = COPs[L];
    const int K = 27 * CI, KP = (K + 31) & ~31;
    const int total = COP * KP;
    for (int i = blockIdx.x * 256 + threadIdx.x; i < total; i += gridDim.x * 256) {
        int jp = i / KP;          // out channel (padded)
        int kp = i - jp * KP;     // k (padded)
        float v = (jp < CO && kp < K) ? a.W[L][(size_t)kp * CO + jp] : 0.f;
        a.dst[L][((size_t)(kp >> 5) * COP + jp) * 32 + (kp & 31)] = (HALF)v;
    }
}

__global__ void convert_x_kernel(const float* __restrict__ x, HALF* __restrict__ xh, int total)
{
    int i = blockIdx.x * 256 + threadIdx.x;
    if (i < total) xh[i] = (HALF)x[i];
}

// ---- conv: barrier-free main loop, direct global->register gather of MFMA fragments.
// FUSED: apply producer's batchnorm+relu on the fly during the gather
// (h holds the producer's RAW pre-norm output; psums = producer sum/sumsq).
template<int CI, int CO_PAD, int NMT, bool FUSED>
__global__ __launch_bounds__(256) void conv_kernel(
    const HALF* __restrict__ h, const int* __restrict__ nbr,
    const HALF* __restrict__ Wt, HALF* __restrict__ yout,
    float* __restrict__ sums, int n,
    const float* __restrict__ psums, const float* __restrict__ pg,
    const float* __restrict__ pb, float pinvn)
{
    constexpr int K   = 27 * CI;
    constexpr int KP  = (K + 31) & ~31;
    constexpr int NCH = KP / 32;
    constexpr int NJB = CO_PAD / 16;
    constexpr int NW  = 4;                       // waves per block
    constexpr int NCB = (CI >= 64) ? 2 : 1;      // distinct channel-bases per lane
    constexpr int LOG2CI = (CI == 64) ? 6 : ((CI == 32) ? 5 : 4);

    __shared__ float red[2][NW][CO_PAD];

    const int wv   = threadIdx.x >> 6;
    const int lane = threadIdx.x & 63;
    const int l15  = lane & 15;
    const int lq   = lane >> 4;
    const int waveRow = blockIdx.x * (NW * 16 * NMT) + wv * (16 * NMT);

    f32x4 acc[NMT][NJB];
#pragma unroll
    for (int mt = 0; mt < NMT; ++mt)
#pragma unroll
        for (int jb = 0; jb < NJB; ++jb)
#pragma unroll
            for (int r = 0; r < 4; ++r) acc[mt][jb][r] = 0.f;

    int nbase[NMT];
#pragma unroll
    for (int mt = 0; mt < NMT; ++mt) {
        const int row = waveRow + mt * 16 + l15;
        nbase[mt] = (row < n) ? row * 27 : -1;
    }

    // per-lane normalization constants for the channel slots this lane gathers
    f16x8 sc8[NCB], bi8[NCB];
    if constexpr (FUSED) {
#pragma unroll
        for (int cb = 0; cb < NCB; ++cb) {
            const int c0 = cb * 32 + ((lq * 8) & (CI - 1));
#pragma unroll
            for (int j = 0; j < 8; ++j) {
                const int c = c0 + j;
                const float mu  = psums[c] * pinvn;
                const float var = psums[CI + c] * pinvn - mu * mu;
                const float sc  = rsqrtf(var + 1e-3f) * pg[c];
                sc8[cb][j] = (HALF)sc;
                bi8[cb][j] = (HALF)(pb[c] - mu * sc);
            }
        }
    }

#pragma unroll 2
    for (int kc = 0; kc < NCH; ++kc) {
        const int kf = kc * 32 + lq * 8;
        const int t  = kf >> LOG2CI;
        const int c  = kf & (CI - 1);
        const int ccb = (NCB == 2) ? (kc & 1) : 0;
        const bool tv = (KP == K) ? true : (t < 27);

        // B fragments: coalesced from tiled Wt
        const HALF* wb = Wt + (size_t)kc * (CO_PAD * 32) + lq * 8;
        f16x8 b[NJB];
#pragma unroll
        for (int jb = 0; jb < NJB; ++jb)
            b[jb] = *(const f16x8*)(wb + (size_t)(jb * 16 + l15) * 32);

#pragma unroll
        for (int mt = 0; mt < NMT; ++mt) {
            int idx = -1;
            if (nbase[mt] >= 0 && tv) idx = nbr[nbase[mt] + t];
            f16x8 a;
#pragma unroll
            for (int j = 0; j < 8; ++j) a[j] = (HALF)0.f;
            if (idx >= 0) {
                a = *(const f16x8*)(h + (size_t)idx * CI + c);
                if constexpr (FUSED) {
                    a = a * sc8[ccb] + bi8[ccb];           // v_pk_fma_f16
#pragma unroll
                    for (int j = 0; j < 8; ++j)
                        a[j] = (a[j] < (HALF)0.f) ? (HALF)0.f : a[j];  // relu
                }
            }
#pragma unroll
            for (int jb = 0; jb < NJB; ++jb)
                acc[mt][jb] = __builtin_amdgcn_mfma_f32_16x16x32_f16(a, b[jb], acc[mt][jb], 0, 0, 0);
        }
    }

    // ---- epilogue: store RAW pre-norm y (fp16) + per-channel sum/sumsq
    // C/D layout: col = lane&15, row = (lane>>4)*4 + reg
#pragma unroll
    for (int jb = 0; jb < NJB; ++jb) {
        const int col = jb * 16 + l15;
        float s = 0.f, sq = 0.f;
#pragma unroll
        for (int mt = 0; mt < NMT; ++mt) {
            const int rb = waveRow + mt * 16 + lq * 4;
#pragma unroll
            for (int r = 0; r < 4; ++r) {
                if (rb + r < n) {
                    const float v = acc[mt][jb][r];
                    yout[(size_t)(rb + r) * CO_PAD + col] = (HALF)v;
                    s += v;
                    sq += v * v;
                }
            }
        }
        s  += __shfl_xor(s, 16);  s  += __shfl_xor(s, 32);
        sq += __shfl_xor(sq, 16); sq += __shfl_xor(sq, 32);
        if (lane < 16) { red[0][wv][col] = s; red[1][wv][col] = sq; }
    }
    __syncthreads();
    if (threadIdx.x < CO_PAD) {
        float s = 0.f, sq = 0.f;
#pragma unroll
        for (int w = 0; w < NW; ++w) { s += red[0][w][threadIdx.x]; sq += red[1][w][threadIdx.x]; }
        atomicAdd(&sums[threadIdx.x], s);
        atomicAdd(&sums[CO_PAD + threadIdx.x], sq);
    }
}

// ---- final: normalize (no relu), co=3 out of CO_PAD=16, fp32 output
__global__ void bn_out_kernel(const HALF* __restrict__ y, const float* __restrict__ sums,
                              const float* __restrict__ g, const float* __restrict__ b,
                              int n, float invn, float* __restrict__ out)
{
    int i = blockIdx.x * 256 + threadIdx.x;
    if (i >= n * 3) return;
    int row = i / 3;
    int c = i - row * 3;
    float mu  = sums[c] * invn;
    float var = sums[16 + c] * invn - mu * mu;
    float sc  = rsqrtf(var + 1e-3f) * g[c];
    out[i] = ((float)y[(size_t)row * 16 + c] - mu) * sc + b[c];
}

extern "C" void kernel_launch(void* const* d_in, const int* in_sizes, int n_in,
                              void* d_out, int out_size, void* d_ws, size_t ws_size,
                              hipStream_t stream)
{
    const int* nbr4  = (const int*)d_in[0];
    const int* inv43 = (const int*)d_in[1];
    const int* nbr3  = (const int*)d_in[2];
    const int* inv32 = (const int*)d_in[3];
    const int* nbr2  = (const int*)d_in[4];
    const int* inv21 = (const int*)d_in[5];
    const int* nbr1  = (const int*)d_in[6];
    const float* x   = (const float*)d_in[7];

    const int n4 = in_sizes[0] / 27;
    const int n3 = in_sizes[1] / 27;
    const int n2 = in_sizes[3] / 27;
    const int n1 = in_sizes[5] / 27;

    // specs: m4,i4,m3,i3,m2,i2,m1,c5
    const int CIs[8]  = {64, 64, 64, 64, 32, 32, 16, 16};
    const int COPs[8] = {64, 64, 64, 32, 32, 16, 16, 16};
    int KPs[8], wtoff[8];
    int wtot = 0;
    for (int s = 0; s < 8; ++s) {
        KPs[s] = ((27 * CIs[s] + 31) / 32) * 32;
        wtoff[s] = wtot;
        wtot += COPs[s] * KPs[s];
    }

    char* ws = (char*)d_ws;
    HALF* wt = (HALF*)ws;
    size_t off = ((size_t)wtot * sizeof(HALF) + 255) & ~(size_t)255;
    float* sums = (float*)(ws + off);
    off += 8 * 128 * sizeof(float);
    off = (off + 255) & ~(size_t)255;
    HALF* xh = (HALF*)(ws + off);
    off += ((size_t)n4 * 64 * sizeof(HALF) + 255) & ~(size_t)255;
    size_t bufElems = 0;
    {
        size_t cand[4] = {(size_t)n4 * 64, (size_t)n3 * 64, (size_t)n2 * 32, (size_t)n1 * 16};
        for (int i = 0; i < 4; ++i) if (cand[i] > bufElems) bufElems = cand[i];
    }
    HALF* Y0 = (HALF*)(ws + off);
    off += (bufElems * sizeof(HALF) + 255) & ~(size_t)255;
    HALF* Y1 = (HALF*)(ws + off);

    hipMemsetAsync(sums, 0, 8 * 128 * sizeof(float), stream);

    WArgs wa;
    for (int s = 0; s < 8; ++s) { wa.W[s] = (const float*)d_in[8 + 3 * s]; wa.dst[s] = wt + wtoff[s]; }
    {
        int maxTotal = 64 * KPs[0];
        dim3 grid((maxTotal + 255) / 256, 8);
        convert_all_w_kernel<<<grid, 256, 0, stream>>>(wa);
    }
    convert_x_kernel<<<(n4 * 64 + 255) / 256, 256, 0, stream>>>(x, xh, n4 * 64);

#define G(s) ((const float*)d_in[9 + 3 * (s)])
#define B(s) ((const float*)d_in[10 + 3 * (s)])
#define SUMS(s) (sums + (s) * 128)
#define GRID(nn) (((nn) + 127) / 128)

    // m4: xh(n4,64) -> Y0 (raw)
    conv_kernel<64, 64, 2, false><<<GRID(n4), 256, 0, stream>>>(
        xh, nbr4, wt + wtoff[0], Y0, SUMS(0), n4, nullptr, nullptr, nullptr, 0.f);
    // i4: norm(m4) fused; Y0(n4) -> Y1(n3)
    conv_kernel<64, 64, 2, true><<<GRID(n3), 256, 0, stream>>>(
        Y0, inv43, wt + wtoff[1], Y1, SUMS(1), n3, SUMS(0), G(0), B(0), 1.f / n4);
    // m3: norm(i4) fused; Y1 -> Y0
    conv_kernel<64, 64, 2, true><<<GRID(n3), 256, 0, stream>>>(
        Y1, nbr3, wt + wtoff[2], Y0, SUMS(2), n3, SUMS(1), G(1), B(1), 1.f / n3);
    // i3: norm(m3) fused; Y0(n3) -> Y1(n2), co 32
    conv_kernel<64, 32, 2, true><<<GRID(n2), 256, 0, stream>>>(
        Y0, inv32, wt + wtoff[3], Y1, SUMS(3), n2, SUMS(2), G(2), B(2), 1.f / n3);
    // m2: norm(i3) fused; Y1 -> Y0
    conv_kernel<32, 32, 2, true><<<GRID(n2), 256, 0, stream>>>(
        Y1, nbr2, wt + wtoff[4], Y0, SUMS(4), n2, SUMS(3), G(3), B(3), 1.f / n2);
    // i2: norm(m2) fused; Y0(n2) -> Y1(n1), co 16
    conv_kernel<32, 16, 2, true><<<GRID(n1), 256, 0, stream>>>(
        Y0, inv21, wt + wtoff[5], Y1, SUMS(5), n1, SUMS(4), G(4), B(4), 1.f / n2);
    // m1: norm(i2) fused; Y1 -> Y0
    conv_kernel<16, 16, 2, true><<<GRID(n1), 256, 0, stream>>>(
        Y1, nbr1, wt + wtoff[6], Y0, SUMS(6), n1, SUMS(5), G(5), B(5), 1.f / n1);
    // c5: norm(m1) fused; Y0 -> Y1 (raw), then fp32 out
    conv_kernel<16, 16, 2, true><<<GRID(n1), 256, 0, stream>>>(
        Y0, nbr1, wt + wtoff[7], Y1, SUMS(7), n1, SUMS(6), G(6), B(6), 1.f / n1);
    bn_out_kernel<<<(n1 * 3 + 255) / 256, 256, 0, stream>>>(
        Y1, SUMS(7), G(7), B(7), n1, 1.f / n1, (float*)d_out);

#undef G
#undef B
#undef SUMS
#undef GRID
}

// Round 4
// 569.703 us; speedup vs baseline: 1.7838x; 1.0431x over previous
//
#include <hip/hip_runtime.h>

typedef _Float16 HALF;
typedef _Float16 f16x8 __attribute__((ext_vector_type(8)));
typedef float f32x4 __attribute__((ext_vector_type(4)));
typedef int i32x4 __attribute__((ext_vector_type(4)));

// ---- fused weight conversion: fp32 (27*CI, CO) -> fp16 tiled [KP/32][CO_PAD][32], zero padded
struct WArgs { const float* W[8]; HALF* dst[8]; };

__global__ void convert_all_w_kernel(WArgs a)
{
    const int CIs[8]  = {64, 64, 64, 64, 32, 32, 16, 16};
    const int COs[8]  = {64, 64, 64, 32, 32, 16, 16, 3};
    const int COPs[8] = {64, 64, 64, 32, 32, 16, 16, 16};
    const int L = blockIdx.y;
    const int CI = CIs[L], CO = COs[L], COP = COPs[L];
    const int K = 27 * CI, KP = (K + 31) & ~31;
    const int total = COP * KP;
    for (int i = blockIdx.x * 256 + threadIdx.x; i < total; i += gridDim.x * 256) {
        int jp = i / KP;          // out channel (padded)
        int kp = i - jp * KP;     // k (padded)
        float v = (jp < CO && kp < K) ? a.W[L][(size_t)kp * CO + jp] : 0.f;
        a.dst[L][((size_t)(kp >> 5) * COP + jp) * 32 + (kp & 31)] = (HALF)v;
    }
}

__global__ void convert_x_kernel(const float* __restrict__ x, HALF* __restrict__ xh, int total)
{
    int i = blockIdx.x * 256 + threadIdx.x;
    if (i < total) xh[i] = (HALF)x[i];
}

// ---- conv: barrier-free, branch-free main loop; all nbr indices preloaded to registers;
// unconditional gathers (clamped addr + post-mask) so the compiler can pipeline loads.
// FUSED: apply producer's batchnorm+relu on the fly during the gather.
template<int CI, int CO_PAD, int NMT, bool FUSED>
__global__ __launch_bounds__(256, 2) void conv_kernel(
    const HALF* __restrict__ h, const int* __restrict__ nbr,
    const HALF* __restrict__ Wt, HALF* __restrict__ yout,
    float* __restrict__ sums, int n,
    const float* __restrict__ psums, const float* __restrict__ pg,
    const float* __restrict__ pb, float pinvn)
{
    constexpr int K    = 27 * CI;
    constexpr int KP   = (K + 31) & ~31;
    constexpr int NCH  = KP / 32;
    constexpr int NJB  = CO_PAD / 16;
    constexpr int NW   = 4;
    constexpr int NCB  = (CI >= 64) ? 2 : 1;
    constexpr int LOG2CI = (CI == 64) ? 6 : ((CI == 32) ? 5 : 4);
    constexpr int NIDX = (CI == 16) ? 14 : 27;   // register-resident taps per m-tile

    __shared__ float red[2][NW][CO_PAD];

    const int wv   = threadIdx.x >> 6;
    const int lane = threadIdx.x & 63;
    const int l15  = lane & 15;
    const int lq   = lane >> 4;
    const int waveRow = blockIdx.x * (NW * 16 * NMT) + wv * (16 * NMT);

    f32x4 acc[NMT][NJB];
#pragma unroll
    for (int mt = 0; mt < NMT; ++mt)
#pragma unroll
        for (int jb = 0; jb < NJB; ++jb)
#pragma unroll
            for (int r = 0; r < 4; ++r) acc[mt][jb][r] = 0.f;

    // ---- preload ALL neighbor indices for this wave's rows (branch-free, independent loads)
    int idxr[NMT][NIDX];
#pragma unroll
    for (int mt = 0; mt < NMT; ++mt) {
        const int row  = waveRow + mt * 16 + l15;
        const bool rok = row < n;
        const int* nb  = nbr + (size_t)min(row, n - 1) * 27;
#pragma unroll
        for (int s = 0; s < NIDX; ++s) {
            const int t = (CI == 16) ? (2 * s + (lq >> 1)) : s;
            const int v = nb[t < 27 ? t : 26];
            idxr[mt][s] = (rok && t < 27) ? v : -1;
        }
    }

    // per-lane normalization constants for the channel slots this lane gathers
    f16x8 sc8[NCB], bi8[NCB];
    if constexpr (FUSED) {
#pragma unroll
        for (int cb = 0; cb < NCB; ++cb) {
            const int c0 = cb * 32 + ((lq * 8) & (CI - 1));
#pragma unroll
            for (int j = 0; j < 8; ++j) {
                const int c = c0 + j;
                const float mu  = psums[c] * pinvn;
                const float var = psums[CI + c] * pinvn - mu * mu;
                const float sc  = rsqrtf(var + 1e-3f) * pg[c];
                sc8[cb][j] = (HALF)sc;
                bi8[cb][j] = (HALF)(pb[c] - mu * sc);
            }
        }
    }

#pragma unroll
    for (int kc = 0; kc < NCH; ++kc) {
        const int c   = (kc * 32 + lq * 8) & (CI - 1);   // channel offset within tap
        const int slot = (CI == 64) ? (kc >> 1) : kc;    // register slot (compile-time)
        const int ccb  = (NCB == 2) ? (kc & 1) : 0;

        // B fragments: coalesced from tiled Wt (L1-resident)
        const HALF* wb = Wt + (size_t)kc * (CO_PAD * 32) + lq * 8;
        f16x8 b[NJB];
#pragma unroll
        for (int jb = 0; jb < NJB; ++jb)
            b[jb] = *(const f16x8*)(wb + (size_t)(jb * 16 + l15) * 32);

#pragma unroll
        for (int mt = 0; mt < NMT; ++mt) {
            const int idx = idxr[mt][slot];
            const int off = (max(idx, 0) << LOG2CI) + c;     // clamped, unconditional
            f16x8 a = *(const f16x8*)(h + off);
            if constexpr (FUSED) {
                a = a * sc8[ccb] + bi8[ccb];                 // v_pk_fma_f16
#pragma unroll
                for (int j = 0; j < 8; ++j)
                    a[j] = (a[j] < (HALF)0.f) ? (HALF)0.f : a[j];
            }
            // zero invalid lanes: mask = 0 if idx<0 (applied AFTER bn so invalid -> exact 0)
            const int m = ~(idx >> 31);
            i32x4 ai = __builtin_bit_cast(i32x4, a);
            ai.x &= m; ai.y &= m; ai.z &= m; ai.w &= m;
            a = __builtin_bit_cast(f16x8, ai);
#pragma unroll
            for (int jb = 0; jb < NJB; ++jb)
                acc[mt][jb] = __builtin_amdgcn_mfma_f32_16x16x32_f16(a, b[jb], acc[mt][jb], 0, 0, 0);
        }
    }

    // ---- epilogue: store RAW pre-norm y (fp16) + per-channel sum/sumsq
    // C/D layout: col = lane&15, row = (lane>>4)*4 + reg
#pragma unroll
    for (int jb = 0; jb < NJB; ++jb) {
        const int col = jb * 16 + l15;
        float s = 0.f, sq = 0.f;
#pragma unroll
        for (int mt = 0; mt < NMT; ++mt) {
            const int rb = waveRow + mt * 16 + lq * 4;
#pragma unroll
            for (int r = 0; r < 4; ++r) {
                if (rb + r < n) {
                    const float v = acc[mt][jb][r];
                    yout[(size_t)(rb + r) * CO_PAD + col] = (HALF)v;
                    s += v;
                    sq += v * v;
                }
            }
        }
        s  += __shfl_xor(s, 16);  s  += __shfl_xor(s, 32);
        sq += __shfl_xor(sq, 16); sq += __shfl_xor(sq, 32);
        if (lane < 16) { red[0][wv][col] = s; red[1][wv][col] = sq; }
    }
    __syncthreads();
    if (threadIdx.x < CO_PAD) {
        float s = 0.f, sq = 0.f;
#pragma unroll
        for (int w = 0; w < NW; ++w) { s += red[0][w][threadIdx.x]; sq += red[1][w][threadIdx.x]; }
        atomicAdd(&sums[threadIdx.x], s);
        atomicAdd(&sums[CO_PAD + threadIdx.x], sq);
    }
}

// ---- final: normalize (no relu), co=3 out of CO_PAD=16, fp32 output
__global__ void bn_out_kernel(const HALF* __restrict__ y, const float* __restrict__ sums,
                              const float* __restrict__ g, const float* __restrict__ b,
                              int n, float invn, float* __restrict__ out)
{
    int i = blockIdx.x * 256 + threadIdx.x;
    if (i >= n * 3) return;
    int row = i / 3;
    int c = i - row * 3;
    float mu  = sums[c] * invn;
    float var = sums[16 + c] * invn - mu * mu;
    float sc  = rsqrtf(var + 1e-3f) * g[c];
    out[i] = ((float)y[(size_t)row * 16 + c] - mu) * sc + b[c];
}

extern "C" void kernel_launch(void* const* d_in, const int* in_sizes, int n_in,
                              void* d_out, int out_size, void* d_ws, size_t ws_size,
                              hipStream_t stream)
{
    const int* nbr4  = (const int*)d_in[0];
    const int* inv43 = (const int*)d_in[1];
    const int* nbr3  = (const int*)d_in[2];
    const int* inv32 = (const int*)d_in[3];
    const int* nbr2  = (const int*)d_in[4];
    const int* inv21 = (const int*)d_in[5];
    const int* nbr1  = (const int*)d_in[6];
    const float* x   = (const float*)d_in[7];

    const int n4 = in_sizes[0] / 27;
    const int n3 = in_sizes[1] / 27;
    const int n2 = in_sizes[3] / 27;
    const int n1 = in_sizes[5] / 27;

    // specs: m4,i4,m3,i3,m2,i2,m1,c5
    const int CIs[8]  = {64, 64, 64, 64, 32, 32, 16, 16};
    const int COPs[8] = {64, 64, 64, 32, 32, 16, 16, 16};
    int KPs[8], wtoff[8];
    int wtot = 0;
    for (int s = 0; s < 8; ++s) {
        KPs[s] = ((27 * CIs[s] + 31) / 32) * 32;
        wtoff[s] = wtot;
        wtot += COPs[s] * KPs[s];
    }

    char* ws = (char*)d_ws;
    HALF* wt = (HALF*)ws;
    size_t off = ((size_t)wtot * sizeof(HALF) + 255) & ~(size_t)255;
    float* sums = (float*)(ws + off);
    off += 8 * 128 * sizeof(float);
    off = (off + 255) & ~(size_t)255;
    HALF* xh = (HALF*)(ws + off);
    off += ((size_t)n4 * 64 * sizeof(HALF) + 255) & ~(size_t)255;
    size_t bufElems = 0;
    {
        size_t cand[4] = {(size_t)n4 * 64, (size_t)n3 * 64, (size_t)n2 * 32, (size_t)n1 * 16};
        for (int i = 0; i < 4; ++i) if (cand[i] > bufElems) bufElems = cand[i];
    }
    HALF* Y0 = (HALF*)(ws + off);
    off += (bufElems * sizeof(HALF) + 255) & ~(size_t)255;
    HALF* Y1 = (HALF*)(ws + off);

    hipMemsetAsync(sums, 0, 8 * 128 * sizeof(float), stream);

    WArgs wa;
    for (int s = 0; s < 8; ++s) { wa.W[s] = (const float*)d_in[8 + 3 * s]; wa.dst[s] = wt + wtoff[s]; }
    {
        int maxTotal = 64 * KPs[0];
        dim3 grid((maxTotal + 255) / 256, 8);
        convert_all_w_kernel<<<grid, 256, 0, stream>>>(wa);
    }
    convert_x_kernel<<<(n4 * 64 + 255) / 256, 256, 0, stream>>>(x, xh, n4 * 64);

#define G(s) ((const float*)d_in[9 + 3 * (s)])
#define B(s) ((const float*)d_in[10 + 3 * (s)])
#define SUMS(s) (sums + (s) * 128)
#define GRID(nn) (((nn) + 127) / 128)

    // m4: xh(n4,64) -> Y0 (raw)
    conv_kernel<64, 64, 2, false><<<GRID(n4), 256, 0, stream>>>(
        xh, nbr4, wt + wtoff[0], Y0, SUMS(0), n4, nullptr, nullptr, nullptr, 0.f);
    // i4: norm(m4) fused; Y0(n4) -> Y1(n3)
    conv_kernel<64, 64, 2, true><<<GRID(n3), 256, 0, stream>>>(
        Y0, inv43, wt + wtoff[1], Y1, SUMS(1), n3, SUMS(0), G(0), B(0), 1.f / n4);
    // m3: norm(i4) fused; Y1 -> Y0
    conv_kernel<64, 64, 2, true><<<GRID(n3), 256, 0, stream>>>(
        Y1, nbr3, wt + wtoff[2], Y0, SUMS(2), n3, SUMS(1), G(1), B(1), 1.f / n3);
    // i3: norm(m3) fused; Y0(n3) -> Y1(n2), co 32
    conv_kernel<64, 32, 2, true><<<GRID(n2), 256, 0, stream>>>(
        Y0, inv32, wt + wtoff[3], Y1, SUMS(3), n2, SUMS(2), G(2), B(2), 1.f / n3);
    // m2: norm(i3) fused; Y1 -> Y0
    conv_kernel<32, 32, 2, true><<<GRID(n2), 256, 0, stream>>>(
        Y1, nbr2, wt + wtoff[4], Y0, SUMS(4), n2, SUMS(3), G(3), B(3), 1.f / n2);
    // i2: norm(m2) fused; Y0(n2) -> Y1(n1), co 16
    conv_kernel<32, 16, 2, true><<<GRID(n1), 256, 0, stream>>>(
        Y0, inv21, wt + wtoff[5], Y1, SUMS(5), n1, SUMS(4), G(4), B(4), 1.f / n2);
    // m1: norm(i2) fused; Y1 -> Y0
    conv_kernel<16, 16, 2, true><<<GRID(n1), 256, 0, stream>>>(
        Y1, nbr1, wt + wtoff[6], Y0, SUMS(6), n1, SUMS(5), G(5), B(5), 1.f / n1);
    // c5: norm(m1) fused; Y0 -> Y1 (raw), then fp32 out
    conv_kernel<16, 16, 2, true><<<GRID(n1), 256, 0, stream>>>(
        Y0, nbr1, wt + wtoff[7], Y1, SUMS(7), n1, SUMS(6), G(6), B(6), 1.f / n1);
    bn_out_kernel<<<(n1 * 3 + 255) / 256, 256, 0, stream>>>(
        Y1, SUMS(7), G(7), B(7), n1, 1.f / n1, (float*)d_out);

#undef G
#undef B
#undef SUMS
#undef GRID
}